// Round 1
// baseline (1146.926 us; speedup 1.0000x reference)
//
#include <hip/hip_runtime.h>
#include <hip/hip_bf16.h>
#include <stdint.h>

#define EMBED 768
#define NH    12
#define HD    64
#define BB    4
#define SSEQ  2048
#define TOK   (BB*SSEQ)          // 8192 tokens
#define ATT_SCALE 0.125f         // 64^-0.5

typedef short  short8  __attribute__((ext_vector_type(8)));
typedef float  floatx4 __attribute__((ext_vector_type(4)));

// round-to-nearest-even fp32 -> bf16 (values are sane, no NaN handling needed)
__device__ __forceinline__ unsigned short f2bf(float f) {
  unsigned int u = __float_as_uint(f);
  return (unsigned short)((u + 0x7fffu + ((u >> 16) & 1u)) >> 16);
}

// async global->LDS, 16B per lane. LDS dest must be wave-uniform base + lane*16.
__device__ __forceinline__ void gl_lds16(const void* gsrc, void* ldst) {
  __builtin_amdgcn_global_load_lds(
      (__attribute__((address_space(1))) void*)(uintptr_t)gsrc,
      (__attribute__((address_space(3))) void*)ldst, 16, 0, 0);
}

// ---------------------------------------------------------------- fp32->bf16
__global__ void cvtk(const float* __restrict__ x, unsigned short* __restrict__ y, int n4) {
  int i = blockIdx.x * blockDim.x + threadIdx.x;
  if (i < n4) {
    float4 v = ((const float4*)x)[i];
    ushort4 o;
    o.x = f2bf(v.x); o.y = f2bf(v.y); o.z = f2bf(v.z); o.w = f2bf(v.w);
    ((ushort4*)y)[i] = o;
  }
}

// ------------------------------------------------- QKV projection: X @ W^T + b
// A = X bf16 [8192 x 768], B = W bf16 [768 x 768] (row-major over k -> B^T GEMM)
// out: bf16 scattered to [b, h, s, d]
__global__ __launch_bounds__(256, 2) void gemm_qkv(
    const unsigned short* __restrict__ Xb,
    const unsigned short* __restrict__ Wqb, const unsigned short* __restrict__ Wkb,
    const unsigned short* __restrict__ Wvb,
    const float* __restrict__ bq, const float* __restrict__ bk, const float* __restrict__ bv,
    unsigned short* __restrict__ Qw, unsigned short* __restrict__ Kw,
    unsigned short* __restrict__ Vw)
{
  __shared__ __align__(16) unsigned short As[128*64];
  __shared__ __align__(16) unsigned short Bs[128*64];
  const int z = blockIdx.z;
  const unsigned short* Wb = (z == 0) ? Wqb : (z == 1) ? Wkb : Wvb;
  const float* bias        = (z == 0) ? bq  : (z == 1) ? bk  : bv;
  unsigned short* Out      = (z == 0) ? Qw  : (z == 1) ? Kw  : Vw;

  const int tid = threadIdx.x;
  const int wid = tid >> 6, lane = tid & 63, quad = lane >> 4, l15 = lane & 15;
  const int wm = (wid >> 1) * 64, wn = (wid & 1) * 64;
  const int m0 = blockIdx.y * 128, n0 = blockIdx.x * 128;

  floatx4 acc[4][4] = {};

  for (int k0 = 0; k0 < EMBED; k0 += 64) {
#pragma unroll
    for (int p = 0; p < 4; ++p) {
      int f = p*256 + tid;
      int row = f >> 3, ch = f & 7;
      gl_lds16(Xb + (size_t)(m0+row)*EMBED + k0 + ch*8, &As[f*8]);
      gl_lds16(Wb + (size_t)(n0+row)*EMBED + k0 + ch*8, &Bs[f*8]);
    }
    __syncthreads();
#pragma unroll
    for (int kk = 0; kk < 2; ++kk) {
      short8 af[4], bf[4];
#pragma unroll
      for (int i = 0; i < 4; ++i)
        af[i] = *(const short8*)&As[(wm + i*16 + l15)*64 + kk*32 + quad*8];
#pragma unroll
      for (int j = 0; j < 4; ++j)
        bf[j] = *(const short8*)&Bs[(wn + j*16 + l15)*64 + kk*32 + quad*8];
#pragma unroll
      for (int i = 0; i < 4; ++i)
#pragma unroll
        for (int j = 0; j < 4; ++j)
          acc[i][j] = __builtin_amdgcn_mfma_f32_16x16x32_bf16(af[i], bf[j], acc[i][j], 0, 0, 0);
    }
    __syncthreads();
  }

#pragma unroll
  for (int j = 0; j < 4; ++j) {
    int n = n0 + wn + j*16 + l15;
    float bia = bias[n];
    int h = n >> 6, d = n & 63;
#pragma unroll
    for (int i = 0; i < 4; ++i) {
#pragma unroll
      for (int r = 0; r < 4; ++r) {
        int m = m0 + wm + i*16 + quad*4 + r;          // C/D: row=(lane>>4)*4+reg
        int b = m >> 11, s = m & 2047;
        Out[(size_t)(b*NH + h)*SSEQ*HD + (size_t)s*HD + d] = f2bf(acc[i][j][r] + bia);
      }
    }
  }
}

// ------------------------------------------------- O projection: A @ Wo^T + bo
// A = attn_pre bf16 [8192 x 768] row-major, out fp32 [8192 x 768]
__global__ __launch_bounds__(256, 2) void gemm_o(
    const unsigned short* __restrict__ Ab, const unsigned short* __restrict__ Wb,
    const float* __restrict__ bias, float* __restrict__ Fo)
{
  __shared__ __align__(16) unsigned short As[128*64];
  __shared__ __align__(16) unsigned short Bs[128*64];
  const int tid = threadIdx.x;
  const int wid = tid >> 6, lane = tid & 63, quad = lane >> 4, l15 = lane & 15;
  const int wm = (wid >> 1) * 64, wn = (wid & 1) * 64;
  const int m0 = blockIdx.y * 128, n0 = blockIdx.x * 128;

  floatx4 acc[4][4] = {};

  for (int k0 = 0; k0 < EMBED; k0 += 64) {
#pragma unroll
    for (int p = 0; p < 4; ++p) {
      int f = p*256 + tid;
      int row = f >> 3, ch = f & 7;
      gl_lds16(Ab + (size_t)(m0+row)*EMBED + k0 + ch*8, &As[f*8]);
      gl_lds16(Wb + (size_t)(n0+row)*EMBED + k0 + ch*8, &Bs[f*8]);
    }
    __syncthreads();
#pragma unroll
    for (int kk = 0; kk < 2; ++kk) {
      short8 af[4], bf[4];
#pragma unroll
      for (int i = 0; i < 4; ++i)
        af[i] = *(const short8*)&As[(wm + i*16 + l15)*64 + kk*32 + quad*8];
#pragma unroll
      for (int j = 0; j < 4; ++j)
        bf[j] = *(const short8*)&Bs[(wn + j*16 + l15)*64 + kk*32 + quad*8];
#pragma unroll
      for (int i = 0; i < 4; ++i)
#pragma unroll
        for (int j = 0; j < 4; ++j)
          acc[i][j] = __builtin_amdgcn_mfma_f32_16x16x32_bf16(af[i], bf[j], acc[i][j], 0, 0, 0);
    }
    __syncthreads();
  }

#pragma unroll
  for (int j = 0; j < 4; ++j) {
    int n = n0 + wn + j*16 + l15;
    float bia = bias[n];
#pragma unroll
    for (int i = 0; i < 4; ++i) {
#pragma unroll
      for (int r = 0; r < 4; ++r) {
        int m = m0 + wm + i*16 + quad*4 + r;
        Fo[(size_t)m*EMBED + n] = acc[i][j][r] + bia;
      }
    }
  }
}

// ------------------------------------------------------------------ attention
// One block per (b*h, 128-query tile). Two passes over K tiles of 64:
//   pass 1: QK^T -> online row max/sumexp (register-only stats, quad shfl-xor)
//   pass 2: recompute QK^T, write normalized P (fp32) to attn_weights,
//           P->LDS(bf16) round-trip into A-layout, O += P @ V via MFMA.
__global__ __launch_bounds__(256, 2) void attn(
    const unsigned short* __restrict__ Qw, const unsigned short* __restrict__ Kw,
    const unsigned short* __restrict__ Vw, unsigned short* __restrict__ AP,
    float* __restrict__ AWout)
{
  __shared__ __align__(16) unsigned short Qs[128*64];   // 16 KB
  __shared__ __align__(16) unsigned short Ks[64*64];    //  8 KB
  __shared__ __align__(16) unsigned short Vt[64*72];    //  9 KB, V^T [d][j], +8 pad
  __shared__ __align__(16) unsigned short Ps[128*72];   // 18 KB, P [m][j], +8 pad
  const int tid = threadIdx.x;
  const int wid = tid >> 6, lane = tid & 63, quad = lane >> 4, l15 = lane & 15;
  const int bh = blockIdx.x;               // 0..47
  const int q0 = blockIdx.y * 128;
  const unsigned short* Qh = Qw + (size_t)bh * SSEQ * HD;
  const unsigned short* Kh = Kw + (size_t)bh * SSEQ * HD;
  const unsigned short* Vh = Vw + (size_t)bh * SSEQ * HD;
  float* aw = AWout + (size_t)bh * SSEQ * SSEQ + (size_t)q0 * SSEQ;

  // stage Q tile (resident for the whole block)
#pragma unroll
  for (int p = 0; p < 4; ++p) {
    int f = p*256 + tid;
    gl_lds16(Qh + (size_t)(q0 + (f >> 3))*HD + (f & 7)*8, &Qs[f*8]);
  }

  float mi[2][4], li[2][4];
#pragma unroll
  for (int mf = 0; mf < 2; ++mf)
#pragma unroll
    for (int r = 0; r < 4; ++r) { mi[mf][r] = -1e30f; li[mf][r] = 0.f; }

  // ---------------- pass 1: row stats ----------------
  for (int kt = 0; kt < SSEQ/64; ++kt) {
    int k0 = kt * 64;
#pragma unroll
    for (int p = 0; p < 2; ++p) {
      int f = p*256 + tid;
      gl_lds16(Kh + (size_t)(k0 + (f >> 3))*HD + (f & 7)*8, &Ks[f*8]);
    }
    __syncthreads();

    floatx4 sa[2][4] = {};
#pragma unroll
    for (int kk = 0; kk < 2; ++kk) {
      short8 qf[2], kf[4];
#pragma unroll
      for (int mf = 0; mf < 2; ++mf)
        qf[mf] = *(const short8*)&Qs[(wid*32 + mf*16 + l15)*64 + kk*32 + quad*8];
#pragma unroll
      for (int nf = 0; nf < 4; ++nf)
        kf[nf] = *(const short8*)&Ks[(nf*16 + l15)*64 + kk*32 + quad*8];
#pragma unroll
      for (int mf = 0; mf < 2; ++mf)
#pragma unroll
        for (int nf = 0; nf < 4; ++nf)
          sa[mf][nf] = __builtin_amdgcn_mfma_f32_16x16x32_bf16(qf[mf], kf[nf], sa[mf][nf], 0, 0, 0);
    }
#pragma unroll
    for (int mf = 0; mf < 2; ++mf) {
#pragma unroll
      for (int r = 0; r < 4; ++r) {
        float s0 = sa[mf][0][r]*ATT_SCALE, s1 = sa[mf][1][r]*ATT_SCALE;
        float s2 = sa[mf][2][r]*ATT_SCALE, s3 = sa[mf][3][r]*ATT_SCALE;
        float tm = fmaxf(fmaxf(s0, s1), fmaxf(s2, s3));
#pragma unroll
        for (int msk = 1; msk < 16; msk <<= 1) tm = fmaxf(tm, __shfl_xor(tm, msk, 16));
        float mn = fmaxf(mi[mf][r], tm);
        float se = __expf(s0-mn) + __expf(s1-mn) + __expf(s2-mn) + __expf(s3-mn);
#pragma unroll
        for (int msk = 1; msk < 16; msk <<= 1) se += __shfl_xor(se, msk, 16);
        li[mf][r] = li[mf][r]*__expf(mi[mf][r]-mn) + se;
        mi[mf][r] = mn;
      }
    }
    __syncthreads();
  }

  float rli[2][4];
#pragma unroll
  for (int mf = 0; mf < 2; ++mf)
#pragma unroll
    for (int r = 0; r < 4; ++r) rli[mf][r] = 1.0f / li[mf][r];

  // ---------------- pass 2: P write + PV ----------------
  floatx4 oa[2][4] = {};
  for (int kt = 0; kt < SSEQ/64; ++kt) {
    int k0 = kt * 64;
#pragma unroll
    for (int p = 0; p < 2; ++p) {
      int f = p*256 + tid;
      gl_lds16(Kh + (size_t)(k0 + (f >> 3))*HD + (f & 7)*8, &Ks[f*8]);
    }
    // stage V transposed: Vt[d][j] = V[k0+j][d]
#pragma unroll
    for (int p = 0; p < 2; ++p) {
      int j = p*32 + (tid >> 3);
      int ch = tid & 7;
      short8 v = *(const short8*)&Vh[(size_t)(k0 + j)*HD + ch*8];
#pragma unroll
      for (int i = 0; i < 8; ++i)
        Vt[(ch*8 + i)*72 + j] = (unsigned short)v[i];
    }
    __syncthreads();

    floatx4 sa[2][4] = {};
#pragma unroll
    for (int kk = 0; kk < 2; ++kk) {
      short8 qf[2], kf[4];
#pragma unroll
      for (int mf = 0; mf < 2; ++mf)
        qf[mf] = *(const short8*)&Qs[(wid*32 + mf*16 + l15)*64 + kk*32 + quad*8];
#pragma unroll
      for (int nf = 0; nf < 4; ++nf)
        kf[nf] = *(const short8*)&Ks[(nf*16 + l15)*64 + kk*32 + quad*8];
#pragma unroll
      for (int mf = 0; mf < 2; ++mf)
#pragma unroll
        for (int nf = 0; nf < 4; ++nf)
          sa[mf][nf] = __builtin_amdgcn_mfma_f32_16x16x32_bf16(qf[mf], kf[nf], sa[mf][nf], 0, 0, 0);
    }

#pragma unroll
    for (int mf = 0; mf < 2; ++mf) {
#pragma unroll
      for (int nf = 0; nf < 4; ++nf) {
#pragma unroll
        for (int r = 0; r < 4; ++r) {
          float p = __expf(sa[mf][nf][r]*ATT_SCALE - mi[mf][r]) * rli[mf][r];
          int rl = wid*32 + mf*16 + quad*4 + r;
          aw[(size_t)rl*SSEQ + k0 + nf*16 + l15] = p;     // attn_weights out (fp32)
          Ps[rl*72 + nf*16 + l15] = f2bf(p);              // P -> A-layout via LDS
        }
      }
    }
    // PV: O[m][d] += P[m][j] * V[j][d]  (A=Ps rows are wave-private; Vt barrier'd above)
#pragma unroll
    for (int kk = 0; kk < 2; ++kk) {
      short8 pf[2], vf[4];
#pragma unroll
      for (int mf = 0; mf < 2; ++mf)
        pf[mf] = *(const short8*)&Ps[(wid*32 + mf*16 + l15)*72 + kk*32 + quad*8];
#pragma unroll
      for (int nd = 0; nd < 4; ++nd)
        vf[nd] = *(const short8*)&Vt[(nd*16 + l15)*72 + kk*32 + quad*8];
#pragma unroll
      for (int mf = 0; mf < 2; ++mf)
#pragma unroll
        for (int nd = 0; nd < 4; ++nd)
          oa[mf][nd] = __builtin_amdgcn_mfma_f32_16x16x32_bf16(pf[mf], vf[nd], oa[mf][nd], 0, 0, 0);
    }
    __syncthreads();
  }

  // epilogue: attn_pre[b, s, h*64+d] bf16
  const int b = bh / NH, h = bh % NH;
#pragma unroll
  for (int mf = 0; mf < 2; ++mf) {
#pragma unroll
    for (int nd = 0; nd < 4; ++nd) {
#pragma unroll
      for (int r = 0; r < 4; ++r) {
        int sq = q0 + wid*32 + mf*16 + quad*4 + r;
        int d  = nd*16 + l15;
        AP[(size_t)(b*SSEQ + sq)*EMBED + h*HD + d] = f2bf(oa[mf][nd][r]);
      }
    }
  }
}

// -------------------------------------------------------------------- launch
extern "C" void kernel_launch(void* const* d_in, const int* in_sizes, int n_in,
                              void* d_out, int out_size, void* d_ws, size_t ws_size,
                              hipStream_t stream) {
  const float* X  = (const float*)d_in[0];
  const float* Wq = (const float*)d_in[1]; const float* bq = (const float*)d_in[2];
  const float* Wk = (const float*)d_in[3]; const float* bk = (const float*)d_in[4];
  const float* Wv = (const float*)d_in[5]; const float* bv = (const float*)d_in[6];
  const float* Wo = (const float*)d_in[7]; const float* bo = (const float*)d_in[8];

  float* outAttn = (float*)d_out;                         // [4,2048,768]
  float* outW    = outAttn + (size_t)TOK * EMBED;         // [4,12,2048,2048]

  // workspace layout (bf16), ~67.6 MB total
  const size_t XN = (size_t)TOK * EMBED;        // 6291456
  const size_t WN = (size_t)EMBED * EMBED;      // 589824
  unsigned short* Xb  = (unsigned short*)d_ws;
  unsigned short* Wqb = Xb  + XN;
  unsigned short* Wkb = Wqb + WN;
  unsigned short* Wvb = Wkb + WN;
  unsigned short* Wob = Wvb + WN;
  unsigned short* Qws = Wob + WN;
  unsigned short* Kws = Qws + XN;
  unsigned short* Vws = Kws + XN;
  unsigned short* APs = Vws + XN;               // attn_pre [b,s,h,d]

  // fp32 -> bf16 conversions
  cvtk<<<dim3((unsigned)(XN/4/256)), 256, 0, stream>>>(X,  Xb,  (int)(XN/4));
  cvtk<<<dim3((unsigned)(WN/4/256)), 256, 0, stream>>>(Wq, Wqb, (int)(WN/4));
  cvtk<<<dim3((unsigned)(WN/4/256)), 256, 0, stream>>>(Wk, Wkb, (int)(WN/4));
  cvtk<<<dim3((unsigned)(WN/4/256)), 256, 0, stream>>>(Wv, Wvb, (int)(WN/4));
  cvtk<<<dim3((unsigned)(WN/4/256)), 256, 0, stream>>>(Wo, Wob, (int)(WN/4));

  // QKV projections -> Q/K/V [b,h,s,d] bf16
  gemm_qkv<<<dim3(EMBED/128, TOK/128, 3), 256, 0, stream>>>(
      Xb, Wqb, Wkb, Wvb, bq, bk, bv, Qws, Kws, Vws);

  // fused attention: attn_weights (fp32, d_out) + attn_pre (bf16, ws)
  attn<<<dim3(BB*NH, SSEQ/128), 256, 0, stream>>>(Qws, Kws, Vws, APs, outW);

  // output projection -> attn_output fp32
  gemm_o<<<dim3(EMBED/128, TOK/128), 256, 0, stream>>>(APs, Wob, bo, outAttn);
}